// Round 1
// baseline (990.666 us; speedup 1.0000x reference)
//
#include <hip/hip_runtime.h>
#include <hip/hip_bf16.h>
#include <math.h>

// Problem constants
#define BB 64
#define SS 2048
#define IN_ 256
#define MSLOT 8
#define HH 8
#define HD_ 64
#define MM 512
#define NG_ 1024

__device__ __forceinline__ float block_sum256(float v, float* red) {
    int t = threadIdx.x;
    red[t] = v; __syncthreads();
    for (int s = 128; s > 0; s >>= 1) {
        if (t < s) red[t] += red[t + s];
        __syncthreads();
    }
    float r = red[0];
    __syncthreads();
    return r;
}

// ---------------- K1a: fused weights WikT[o][i] = sum_j Wi[i][j]*Wk[j][o]; bkf[o]=bi@Wk+bk
__global__ __launch_bounds__(256) void k_fuse_w(const float* __restrict__ Wi,
                                                const float* __restrict__ Wk,
                                                const float* __restrict__ Wv,
                                                const float* __restrict__ bi,
                                                const float* __restrict__ bk,
                                                const float* __restrict__ bv,
                                                float* __restrict__ WikT,
                                                float* __restrict__ WivT,
                                                float* __restrict__ bkf,
                                                float* __restrict__ bvf) {
    int blk = blockIdx.x;          // 0..1023
    int which = blk >> 9;          // 0: k, 1: v
    int o = blk & 511;
    const float* W = which ? Wv : Wk;
    const float* bx = which ? bv : bk;
    float* WT = which ? WivT : WikT;
    float* bf = which ? bvf : bkf;

    __shared__ float col[512];
    __shared__ float red[256];
    int t = threadIdx.x;
    col[t]       = W[t * 512 + o];
    col[t + 256] = W[(t + 256) * 512 + o];
    __syncthreads();

    const float* wi_row = Wi + t * 512;   // t = i (0..255)
    float acc = 0.f;
    for (int j = 0; j < 512; ++j) acc += wi_row[j] * col[j];
    WT[o * 256 + t] = acc;

    float p = bi[t] * col[t] + bi[t + 256] * col[t + 256];
    float s = block_sum256(p, red);
    if (t == 0) bf[o] = s + bx[o];
}

// ---------------- K1b: q[b,ms,o] = memory[b,ms,:]@Wq + bq
__global__ __launch_bounds__(256) void k_q(const float* __restrict__ memory,
                                           const float* __restrict__ Wq,
                                           const float* __restrict__ bq,
                                           float* __restrict__ q) {
    int bms = blockIdx.x;
    __shared__ float row[512];
    int t = threadIdx.x;
    row[t]       = memory[bms * 512 + t];
    row[t + 256] = memory[bms * 512 + t + 256];
    __syncthreads();
    for (int oo = 0; oo < 2; ++oo) {
        int o = oo * 256 + t;
        float acc = bq[o];
        for (int j = 0; j < 512; ++j) acc += row[j] * Wq[j * 512 + o];
        q[bms * 512 + o] = acc;
    }
}

// ---------------- K1c: P[b,hm,i] = sum_d q[b,ms,h*64+d]*WikT[h*64+d][i]; c[b,hm]=sum_d q*bkf
__global__ __launch_bounds__(256) void k_p(const float* __restrict__ q,
                                           const float* __restrict__ WikT,
                                           const float* __restrict__ bkf,
                                           float* __restrict__ P,
                                           float* __restrict__ cbuf) {
    int blk = blockIdx.x;           // b*64 + hm, hm = h*8+ms
    int b = blk >> 6, hm = blk & 63;
    int h = hm >> 3, ms = hm & 7;
    int t = threadIdx.x;
    __shared__ float qv[64];
    __shared__ float red[64];
    if (t < 64) qv[t] = q[(b * 8 + ms) * 512 + h * 64 + t];
    __syncthreads();
    float acc = 0.f;
    for (int d = 0; d < 64; ++d) acc += qv[d] * WikT[(h * 64 + d) * 256 + t];
    P[blk * 256 + t] = acc;
    if (t < 64) red[t] = qv[t] * bkf[h * 64 + t];
    __syncthreads();
    for (int s = 32; s > 0; s >>= 1) {
        if (t < s) red[t] += red[t + s];
        __syncthreads();
    }
    if (t == 0) cbuf[blk] = red[0];
}

// ---------------- K2: scores[b,hm,s] = P[b,hm,:]·inputs[b,s,:] + c[b,hm]
__global__ __launch_bounds__(256) void k_scores(const float* __restrict__ inputs,
                                                const float* __restrict__ P,
                                                const float* __restrict__ cbuf,
                                                float* __restrict__ scores) {
    int b = blockIdx.y;
    int sbase = blockIdx.x * 128;
    int t = threadIdx.x;
    int sg = t & 31, hg = t >> 5;   // hg 0..7
    __shared__ float Pl[64 * 33];
    __shared__ float Il[128 * 33];
    float acc[8][4];
#pragma unroll
    for (int a = 0; a < 8; ++a)
#pragma unroll
        for (int c2 = 0; c2 < 4; ++c2) acc[a][c2] = 0.f;

    for (int ic = 0; ic < 8; ++ic) {
#pragma unroll
        for (int k = 0; k < 8; ++k) {
            int idx = t + k * 256;
            int hm_l = idx >> 5, i_l = idx & 31;
            Pl[hm_l * 33 + i_l] = P[(b * 64 + hm_l) * 256 + ic * 32 + i_l];
        }
#pragma unroll
        for (int k = 0; k < 16; ++k) {
            int idx = t + k * 256;
            int r = idx >> 5, cc = idx & 31;
            Il[r * 33 + cc] = inputs[((size_t)b * SS + sbase + r) * IN_ + ic * 32 + cc];
        }
        __syncthreads();
        for (int i = 0; i < 32; ++i) {
            float pv[8], sv[4];
#pragma unroll
            for (int jh = 0; jh < 8; ++jh) pv[jh] = Pl[(hg + 8 * jh) * 33 + i];
#pragma unroll
            for (int js = 0; js < 4; ++js) sv[js] = Il[(sg + 32 * js) * 33 + i];
#pragma unroll
            for (int jh = 0; jh < 8; ++jh)
#pragma unroll
                for (int js = 0; js < 4; ++js) acc[jh][js] += pv[jh] * sv[js];
        }
        __syncthreads();
    }
#pragma unroll
    for (int jh = 0; jh < 8; ++jh) {
        int hm = hg + 8 * jh;
        float cv = cbuf[b * 64 + hm];
#pragma unroll
        for (int js = 0; js < 4; ++js) {
            int s = sbase + sg + 32 * js;
            scores[((size_t)b * 64 + hm) * SS + s] = acc[jh][js] + cv;
        }
    }
}

// ---------------- K3: per-row softmax + top-3 (no renormalization)
__global__ __launch_bounds__(256) void k_topk(const float* __restrict__ scores,
                                              float* __restrict__ topk_p,
                                              int* __restrict__ topk_idx) {
    int row = blockIdx.x;   // b*64 + hm
    const float* sr = scores + (size_t)row * SS;
    int t = threadIdx.x;
    float v[8];
#pragma unroll
    for (int k = 0; k < 8; ++k) v[k] = sr[k * 256 + t];

    __shared__ float red[256];
    __shared__ float vred[256];
    __shared__ int ired[256];

    float m = -INFINITY;
#pragma unroll
    for (int k = 0; k < 8; ++k) m = fmaxf(m, v[k]);
    red[t] = m; __syncthreads();
    for (int s = 128; s > 0; s >>= 1) {
        if (t < s) red[t] = fmaxf(red[t], red[t + s]);
        __syncthreads();
    }
    float rowmax = red[0]; __syncthreads();

    float sum = 0.f;
#pragma unroll
    for (int k = 0; k < 8; ++k) sum += expf(v[k] - rowmax);
    float rowsum = block_sum256(sum, red);

    int found[3]; float fval[3];
    for (int r = 0; r < 3; ++r) {
        float bv = -INFINITY; int bidx = 0x7fffffff;
#pragma unroll
        for (int k = 0; k < 8; ++k) {
            int gi = k * 256 + t;
            bool skip = false;
            for (int j = 0; j < r; ++j) skip = skip || (found[j] == gi);
            float val = skip ? -INFINITY : v[k];
            if (val > bv || (val == bv && gi < bidx)) { bv = val; bidx = gi; }
        }
        vred[t] = bv; ired[t] = bidx; __syncthreads();
        for (int s = 128; s > 0; s >>= 1) {
            if (t < s) {
                float ov = vred[t + s]; int oi = ired[t + s];
                if (ov > vred[t] || (ov == vred[t] && oi < ired[t])) { vred[t] = ov; ired[t] = oi; }
            }
            __syncthreads();
        }
        found[r] = ired[0];
        fval[r] = vred[0];
        __syncthreads();
    }
    if (t == 0) {
#pragma unroll
        for (int r = 0; r < 3; ++r) {
            topk_idx[row * 3 + r] = found[r];
            topk_p[row * 3 + r] = expf(fval[r] - rowmax) / rowsum;
        }
    }
}

// ---------------- K4: att[b,ms,o] = sum_j p_j * (inputs[b,s_j,:]@WivT[o,:] + bvf[o])
__global__ __launch_bounds__(256) void k_att(const float* __restrict__ inputs,
                                             const float* __restrict__ WivT,
                                             const float* __restrict__ bvf,
                                             const float* __restrict__ topk_p,
                                             const int* __restrict__ topk_idx,
                                             float* __restrict__ att) {
    int bms = blockIdx.x;           // b*8 + ms
    int b = bms >> 3, ms = bms & 7;
    int t = threadIdx.x;
    for (int oo = 0; oo < 2; ++oo) {
        int o = oo * 256 + t;
        int h = o >> 6;
        int hm = h * 8 + ms;
        const float* wr = WivT + o * 256;
        float acc = 0.f;
#pragma unroll
        for (int j = 0; j < 3; ++j) {
            int sj = topk_idx[(b * 64 + hm) * 3 + j];
            float pj = topk_p[(b * 64 + hm) * 3 + j];
            const float* inr = inputs + ((size_t)b * SS + sj) * IN_;
            float dot = 0.f;
            for (int i = 0; i < 256; ++i) dot += inr[i] * wr[i];
            acc += pj * (dot + bvf[o]);
        }
        att[bms * 512 + o] = acc;
    }
}

// ---------------- K5: gi_acc[b,d] += sum_s relu(rw[d]*(inputs[b,s,:]@Wi[:,d] + bi[d]))
__global__ __launch_bounds__(256) void k_gimean(const float* __restrict__ inputs,
                                                const float* __restrict__ Wi,
                                                const float* __restrict__ bi,
                                                const float* __restrict__ rw,
                                                float* __restrict__ gi_acc) {
    int stile = blockIdx.x;   // 0..31 (64 s each)
    int dh = blockIdx.y;      // 0..1 (256 d each)
    int b = blockIdx.z;
    int sbase = stile * 64;
    int t = threadIdx.x;
    int sg = t & 7, dg = t >> 3;   // dg 0..31

    __shared__ float Il[64 * 33];
    __shared__ float Wl[32 * 257];
    __shared__ float part[256];
    part[t] = 0.f;

    float acc[8][8];
#pragma unroll
    for (int a = 0; a < 8; ++a)
#pragma unroll
        for (int c2 = 0; c2 < 8; ++c2) acc[a][c2] = 0.f;

    for (int ic = 0; ic < 8; ++ic) {
#pragma unroll
        for (int k = 0; k < 8; ++k) {
            int idx = t + k * 256;
            int r = idx >> 5, cc = idx & 31;
            Il[r * 33 + cc] = inputs[((size_t)b * SS + sbase + r) * IN_ + ic * 32 + cc];
        }
#pragma unroll
        for (int k = 0; k < 32; ++k) {
            int idx = t + k * 256;
            int i_l = idx >> 8, d_l = idx & 255;
            Wl[i_l * 257 + d_l] = Wi[(ic * 32 + i_l) * 512 + dh * 256 + d_l];
        }
        __syncthreads();
        for (int i = 0; i < 32; ++i) {
            float wv[8], iv[8];
#pragma unroll
            for (int jd = 0; jd < 8; ++jd) wv[jd] = Wl[i * 257 + dg + 32 * jd];
#pragma unroll
            for (int js = 0; js < 8; ++js) iv[js] = Il[(sg * 8 + js) * 33 + i];
#pragma unroll
            for (int js = 0; js < 8; ++js)
#pragma unroll
                for (int jd = 0; jd < 8; ++jd) acc[js][jd] += iv[js] * wv[jd];
        }
        __syncthreads();
    }
#pragma unroll
    for (int jd = 0; jd < 8; ++jd) {
        int d = dh * 256 + dg + 32 * jd;
        float bid = bi[d], rwd = rw[d];
        float s8 = 0.f;
#pragma unroll
        for (int js = 0; js < 8; ++js) {
            float x = acc[js][jd] + bid;
            s8 += fmaxf(rwd * x, 0.f);
        }
        atomicAdd(&part[dg + 32 * jd], s8);
    }
    __syncthreads();
    atomicAdd(&gi_acc[b * 512 + dh * 256 + t], part[t]);
}

// ---------------- K6a: gate_in[b,o] = (gi_acc[b,:]/S)@Wr + br
__global__ __launch_bounds__(256) void k_gatein(const float* __restrict__ gi_acc,
                                                const float* __restrict__ Wr,
                                                const float* __restrict__ br,
                                                float* __restrict__ gate_in) {
    int b = blockIdx.x;
    int t = threadIdx.x;
    __shared__ float gm[512];
    gm[t]       = gi_acc[b * 512 + t] * (1.0f / 2048.0f);
    gm[t + 256] = gi_acc[b * 512 + t + 256] * (1.0f / 2048.0f);
    __syncthreads();
    for (int oo = 0; oo < 4; ++oo) {
        int o = oo * 256 + t;
        float acc = br[o];
        for (int d = 0; d < 512; ++d) acc += gm[d] * Wr[d * 1024 + o];
        gate_in[b * 1024 + o] = acc;
    }
}

// ---------------- K6b: LN1 -> mlp x2 -> LN2 -> gates -> output
__global__ __launch_bounds__(256) void k_final(const float* __restrict__ memory,
                                               const float* __restrict__ att,
                                               const float* __restrict__ Wmlp,
                                               const float* __restrict__ bmlp,
                                               const float* __restrict__ g1,
                                               const float* __restrict__ b1,
                                               const float* __restrict__ g2,
                                               const float* __restrict__ b2,
                                               const float* __restrict__ Wg,
                                               const float* __restrict__ gate_in,
                                               const float* __restrict__ fb,
                                               const float* __restrict__ ib,
                                               float* __restrict__ out) {
    int bms = blockIdx.x;
    int b = bms >> 3, ms = bms & 7;
    int t = threadIdx.x;
    __shared__ float mem1[512];
    __shared__ float tmem[512];
    __shared__ float buf[512];
    __shared__ float red[256];

    float m0 = memory[bms * 512 + t], m1 = memory[bms * 512 + t + 256];
    float a0 = att[bms * 512 + t],    a1 = att[bms * 512 + t + 256];
    tmem[t] = tanhf(m0); tmem[t + 256] = tanhf(m1);
    float x0 = m0 + a0, x1 = m1 + a1;

    float mu = block_sum256(x0 + x1, red) * (1.f / 512.f);
    float d0 = x0 - mu, d1 = x1 - mu;
    float var = block_sum256(d0 * d0 + d1 * d1, red) * (1.f / 512.f);
    float rstd = rsqrtf(var + 1e-5f);
    mem1[t]       = d0 * rstd * g1[t] + b1[t];
    mem1[t + 256] = d1 * rstd * g1[t + 256] + b1[t + 256];
    __syncthreads();

    // mlp layer 1
    float r0 = bmlp[t], r1 = bmlp[t + 256];
    for (int d = 0; d < 512; ++d) {
        float md = mem1[d];
        r0 += md * Wmlp[d * 512 + t];
        r1 += md * Wmlp[d * 512 + t + 256];
    }
    r0 = fmaxf(r0, 0.f); r1 = fmaxf(r1, 0.f);
    buf[t] = r0; buf[t + 256] = r1;
    __syncthreads();

    // mlp layer 2 (shared weights)
    float q0 = bmlp[t], q1 = bmlp[t + 256];
    for (int d = 0; d < 512; ++d) {
        float md = buf[d];
        q0 += md * Wmlp[d * 512 + t];
        q1 += md * Wmlp[d * 512 + t + 256];
    }
    q0 = fmaxf(q0, 0.f); q1 = fmaxf(q1, 0.f);

    float y0 = mem1[t] + q0, y1 = mem1[t + 256] + q1;
    float mu2 = block_sum256(y0 + y1, red) * (1.f / 512.f);
    float e0 = y0 - mu2, e1 = y1 - mu2;
    float var2 = block_sum256(e0 * e0 + e1 * e1, red) * (1.f / 512.f);
    float rstd2 = rsqrtf(var2 + 1e-5f);
    float np0 = e0 * rstd2 * g2[t] + b2[t];
    float np1 = e1 * rstd2 * g2[t + 256] + b2[t + 256];

    // gates
    float ib_ = ib[0], fb_ = fb[0];
    const float* Wgm = Wg + (size_t)ms * 512 * 1024;
    float ig0 = gate_in[b * 1024 + t],       ig1 = gate_in[b * 1024 + t + 256];
    float fg0 = gate_in[b * 1024 + 512 + t], fg1 = gate_in[b * 1024 + 512 + t + 256];
    for (int j = 0; j < 512; ++j) {
        float tm = tmem[j];
        const float* wr = Wgm + (size_t)j * 1024;
        ig0 += tm * wr[t];       ig1 += tm * wr[t + 256];
        fg0 += tm * wr[512 + t]; fg1 += tm * wr[512 + t + 256];
    }
    float s_ig0 = 1.f / (1.f + expf(-(ig0 + ib_)));
    float s_ig1 = 1.f / (1.f + expf(-(ig1 + ib_)));
    float s_fg0 = 1.f / (1.f + expf(-(fg0 + fb_)));
    float s_fg1 = 1.f / (1.f + expf(-(fg1 + fb_)));
    out[bms * 512 + t]       = s_ig0 * tanhf(np0) + s_fg0 * m0;
    out[bms * 512 + t + 256] = s_ig1 * tanhf(np1) + s_fg1 * m1;
}

extern "C" void kernel_launch(void* const* d_in, const int* in_sizes, int n_in,
                              void* d_out, int out_size, void* d_ws, size_t ws_size,
                              hipStream_t stream) {
    const float* inputs = (const float*)d_in[0];
    const float* memory = (const float*)d_in[1];
    const float* Wq  = (const float*)d_in[2];
    const float* bq  = (const float*)d_in[3];
    const float* Wk  = (const float*)d_in[4];
    const float* bk  = (const float*)d_in[5];
    const float* Wv  = (const float*)d_in[6];
    const float* bv  = (const float*)d_in[7];
    const float* Wmlp= (const float*)d_in[8];
    const float* bmlp= (const float*)d_in[9];
    const float* g1  = (const float*)d_in[10];
    const float* b1  = (const float*)d_in[11];
    const float* g2  = (const float*)d_in[12];
    const float* b2  = (const float*)d_in[13];
    const float* Wi  = (const float*)d_in[14];
    const float* bi  = (const float*)d_in[15];
    const float* rw  = (const float*)d_in[16];
    const float* Wr  = (const float*)d_in[17];
    const float* br  = (const float*)d_in[18];
    const float* Wg  = (const float*)d_in[19];
    const float* fb  = (const float*)d_in[20];
    const float* ib  = (const float*)d_in[21];
    float* out = (float*)d_out;

    float* ws = (float*)d_ws;
    float* WikT   = ws + 0;          // 512*256
    float* WivT   = ws + 131072;     // 512*256
    float* bkf    = ws + 262144;     // 512
    float* bvf    = ws + 262656;     // 512
    float* qbuf   = ws + 263168;     // 64*8*512
    float* P      = ws + 525312;     // 64*64*256
    float* cbuf   = ws + 1573888;    // 64*64
    float* scores = ws + 1577984;    // 64*64*2048
    float* topkp  = ws + 9966592;    // 64*64*3
    int*   topki  = (int*)(ws + 9978880); // 64*64*3
    float* att    = ws + 9991168;    // 64*8*512
    float* giacc  = ws + 10253312;   // 64*512
    float* gatein = ws + 10286080;   // 64*1024

    hipMemsetAsync(giacc, 0, (size_t)BB * 512 * sizeof(float), stream);

    k_fuse_w<<<1024, 256, 0, stream>>>(Wi, Wk, Wv, bi, bk, bv, WikT, WivT, bkf, bvf);
    k_q<<<512, 256, 0, stream>>>(memory, Wq, bq, qbuf);
    k_p<<<4096, 256, 0, stream>>>(qbuf, WikT, bkf, P, cbuf);
    k_scores<<<dim3(16, 64), 256, 0, stream>>>(inputs, P, cbuf, scores);
    k_topk<<<4096, 256, 0, stream>>>(scores, topkp, topki);
    k_att<<<512, 256, 0, stream>>>(inputs, WivT, bvf, topkp, topki, att);
    k_gimean<<<dim3(32, 2, 64), 256, 0, stream>>>(inputs, Wi, bi, rw, giacc);
    k_gatein<<<64, 256, 0, stream>>>(giacc, Wr, br, gatein);
    k_final<<<512, 256, 0, stream>>>(memory, att, Wmlp, bmlp, g1, b1, g2, b2, Wg,
                                     gatein, fb, ib, out);
}

// Round 2
// 517.095 us; speedup vs baseline: 1.9158x; 1.9158x over previous
//
#include <hip/hip_runtime.h>
#include <hip/hip_bf16.h>
#include <math.h>

// Problem constants
#define BB 64
#define SS 2048
#define IN_ 256
#define MSLOT 8
#define HH 8
#define HD_ 64
#define MM 512
#define NG_ 1024

typedef __attribute__((ext_vector_type(8))) short short8;
typedef __attribute__((ext_vector_type(8))) unsigned short ushort8;
typedef __attribute__((ext_vector_type(4))) float f32x4;

__device__ __forceinline__ unsigned short f2bf(float f) {
    unsigned int u = __builtin_bit_cast(unsigned int, f);
    u += 0x7fff + ((u >> 16) & 1);   // round-to-nearest-even
    return (unsigned short)(u >> 16);
}

__device__ __forceinline__ float block_sum256(float v, float* red) {
    int t = threadIdx.x;
    red[t] = v; __syncthreads();
    for (int s = 128; s > 0; s >>= 1) {
        if (t < s) red[t] += red[t + s];
        __syncthreads();
    }
    float r = red[0];
    __syncthreads();
    return r;
}

// ---- LDS tile staging helpers: 64 rows x 256 cols bf16, 16B-chunk XOR swizzle
// chunk c (8 shorts) of row r stored at chunk (c ^ (r&7)).
__device__ __forceinline__ void stage_tile_bf16(unsigned short* lds,
                                                const unsigned short* __restrict__ src,
                                                int t) {
#pragma unroll
    for (int it = 0; it < 8; ++it) {
        int c = t + it * 256;
        int r = c >> 5, ch = c & 31;
        ushort8 v = *(const ushort8*)(src + (size_t)r * 256 + ch * 8);
        int sch = ch ^ (r & 7);
        *(ushort8*)(lds + r * 256 + sch * 8) = v;
    }
}

__device__ __forceinline__ void stage_tile_f32cvt(unsigned short* lds,
                                                  const float* __restrict__ src,
                                                  int t) {
#pragma unroll
    for (int it = 0; it < 8; ++it) {
        int c = t + it * 256;
        int r = c >> 5, ch = c & 31;
        const float* p = src + (size_t)r * 256 + ch * 8;
        float4 f0 = *(const float4*)p;
        float4 f1 = *(const float4*)(p + 4);
        ushort8 v;
        v[0] = f2bf(f0.x); v[1] = f2bf(f0.y); v[2] = f2bf(f0.z); v[3] = f2bf(f0.w);
        v[4] = f2bf(f1.x); v[5] = f2bf(f1.y); v[6] = f2bf(f1.z); v[7] = f2bf(f1.w);
        int sch = ch ^ (r & 7);
        *(ushort8*)(lds + r * 256 + sch * 8) = v;
    }
}

__device__ __forceinline__ short8 frag_ld(const unsigned short* lds, int row, int chunk) {
    int sch = chunk ^ (row & 7);
    return *(const short8*)(lds + row * 256 + sch * 8);
}

// ---------------- K1a: fused weights WikT[o][i] = sum_j Wi[i][j]*Wk[j][o]; bkf[o]=bi@Wk+bk
__global__ __launch_bounds__(256) void k_fuse_w(const float* __restrict__ Wi,
                                                const float* __restrict__ Wk,
                                                const float* __restrict__ Wv,
                                                const float* __restrict__ bi,
                                                const float* __restrict__ bk,
                                                const float* __restrict__ bv,
                                                float* __restrict__ WikT,
                                                float* __restrict__ WivT,
                                                float* __restrict__ bkf,
                                                float* __restrict__ bvf) {
    int blk = blockIdx.x;          // 0..1023
    int which = blk >> 9;          // 0: k, 1: v
    int o = blk & 511;
    const float* W = which ? Wv : Wk;
    const float* bx = which ? bv : bk;
    float* WT = which ? WivT : WikT;
    float* bf = which ? bvf : bkf;

    __shared__ float col[512];
    __shared__ float red[256];
    int t = threadIdx.x;
    col[t]       = W[t * 512 + o];
    col[t + 256] = W[(t + 256) * 512 + o];
    __syncthreads();

    const float* wi_row = Wi + t * 512;   // t = i (0..255)
    float acc = 0.f;
    for (int j = 0; j < 512; ++j) acc += wi_row[j] * col[j];
    WT[o * 256 + t] = acc;

    float p = bi[t] * col[t] + bi[t + 256] * col[t + 256];
    float s = block_sum256(p, red);
    if (t == 0) bf[o] = s + bx[o];
}

// ---------------- K1b: q[b,ms,o] = memory[b,ms,:]@Wq + bq
__global__ __launch_bounds__(256) void k_q(const float* __restrict__ memory,
                                           const float* __restrict__ Wq,
                                           const float* __restrict__ bq,
                                           float* __restrict__ q) {
    int bms = blockIdx.x;
    __shared__ float row[512];
    int t = threadIdx.x;
    row[t]       = memory[bms * 512 + t];
    row[t + 256] = memory[bms * 512 + t + 256];
    __syncthreads();
    for (int oo = 0; oo < 2; ++oo) {
        int o = oo * 256 + t;
        float acc = bq[o];
        for (int j = 0; j < 512; ++j) acc += row[j] * Wq[j * 512 + o];
        q[bms * 512 + o] = acc;
    }
}

// ---------------- K1c: P[b,hm,i] (bf16) = sum_d q[b,ms,h*64+d]*WikT[h*64+d][i]; c[b,hm]=sum_d q*bkf
__global__ __launch_bounds__(256) void k_p(const float* __restrict__ q,
                                           const float* __restrict__ WikT,
                                           const float* __restrict__ bkf,
                                           unsigned short* __restrict__ Pb,
                                           float* __restrict__ cbuf) {
    int blk = blockIdx.x;           // b*64 + hm, hm = h*8+ms
    int b = blk >> 6, hm = blk & 63;
    int h = hm >> 3, ms = hm & 7;
    int t = threadIdx.x;
    __shared__ float qv[64];
    __shared__ float red[64];
    if (t < 64) qv[t] = q[(b * 8 + ms) * 512 + h * 64 + t];
    __syncthreads();
    float acc = 0.f;
    for (int d = 0; d < 64; ++d) acc += qv[d] * WikT[(h * 64 + d) * 256 + t];
    Pb[blk * 256 + t] = f2bf(acc);
    if (t < 64) red[t] = qv[t] * bkf[h * 64 + t];
    __syncthreads();
    for (int s = 32; s > 0; s >>= 1) {
        if (t < s) red[t] += red[t + s];
        __syncthreads();
    }
    if (t == 0) cbuf[blk] = red[0];
}

// ---------------- Wi^T -> bf16
__global__ __launch_bounds__(256) void k_wiT(const float* __restrict__ Wi,
                                             unsigned short* __restrict__ WiTb) {
    int d = blockIdx.x;      // 0..511
    int k = threadIdx.x;     // 0..255
    WiTb[d * 256 + k] = f2bf(Wi[k * 512 + d]);
}

// ---------------- K2 (MFMA): scores[b,hm,s] = P[b,hm,:]·inputs[b,s,:] + c[b,hm]
__global__ __launch_bounds__(256) void k_scores_mfma(const float* __restrict__ inputs,
                                                     const unsigned short* __restrict__ Pb,
                                                     const float* __restrict__ cbuf,
                                                     float* __restrict__ scores) {
    __shared__ unsigned short Pl[64 * 256];
    __shared__ unsigned short Il[64 * 256];
    int t = threadIdx.x;
    int stile = blockIdx.x;   // 0..31 (64 s each)
    int b = blockIdx.y;

    stage_tile_bf16(Pl, Pb + (size_t)b * 64 * 256, t);
    const float* src = inputs + ((size_t)b * SS + stile * 64) * IN_;
    stage_tile_f32cvt(Il, src, t);
    __syncthreads();

    int l = t & 63, w = t >> 6;
    int kg = l >> 4, r16 = l & 15;
    short8 a[8];
#pragma unroll
    for (int kk = 0; kk < 8; ++kk) a[kk] = frag_ld(Pl, w * 16 + r16, kk * 4 + kg);

#pragma unroll
    for (int nt = 0; nt < 4; ++nt) {
        f32x4 acc = {0.f, 0.f, 0.f, 0.f};
#pragma unroll
        for (int kk = 0; kk < 8; ++kk) {
            short8 bf = frag_ld(Il, nt * 16 + r16, kk * 4 + kg);
            acc = __builtin_amdgcn_mfma_f32_16x16x32_bf16(a[kk], bf, acc, 0, 0, 0);
        }
        int s = stile * 64 + nt * 16 + r16;
#pragma unroll
        for (int j = 0; j < 4; ++j) {
            int hm = w * 16 + kg * 4 + j;
            scores[((size_t)(b * 64 + hm)) * SS + s] = acc[j] + cbuf[b * 64 + hm];
        }
    }
}

// ---------------- K3: per-row softmax + top-3 (no renormalization)
__global__ __launch_bounds__(256) void k_topk(const float* __restrict__ scores,
                                              float* __restrict__ topk_p,
                                              int* __restrict__ topk_idx) {
    int row = blockIdx.x;   // b*64 + hm
    const float* sr = scores + (size_t)row * SS;
    int t = threadIdx.x;
    float v[8];
#pragma unroll
    for (int k = 0; k < 8; ++k) v[k] = sr[k * 256 + t];

    __shared__ float red[256];
    __shared__ float vred[256];
    __shared__ int ired[256];

    float m = -INFINITY;
#pragma unroll
    for (int k = 0; k < 8; ++k) m = fmaxf(m, v[k]);
    red[t] = m; __syncthreads();
    for (int s = 128; s > 0; s >>= 1) {
        if (t < s) red[t] = fmaxf(red[t], red[t + s]);
        __syncthreads();
    }
    float rowmax = red[0]; __syncthreads();

    float sum = 0.f;
#pragma unroll
    for (int k = 0; k < 8; ++k) sum += expf(v[k] - rowmax);
    float rowsum = block_sum256(sum, red);

    int found[3]; float fval[3];
    for (int r = 0; r < 3; ++r) {
        float bv = -INFINITY; int bidx = 0x7fffffff;
#pragma unroll
        for (int k = 0; k < 8; ++k) {
            int gi = k * 256 + t;
            bool skip = false;
            for (int j = 0; j < r; ++j) skip = skip || (found[j] == gi);
            float val = skip ? -INFINITY : v[k];
            if (val > bv || (val == bv && gi < bidx)) { bv = val; bidx = gi; }
        }
        vred[t] = bv; ired[t] = bidx; __syncthreads();
        for (int s = 128; s > 0; s >>= 1) {
            if (t < s) {
                float ov = vred[t + s]; int oi = ired[t + s];
                if (ov > vred[t] || (ov == vred[t] && oi < ired[t])) { vred[t] = ov; ired[t] = oi; }
            }
            __syncthreads();
        }
        found[r] = ired[0];
        fval[r] = vred[0];
        __syncthreads();
    }
    if (t == 0) {
#pragma unroll
        for (int r = 0; r < 3; ++r) {
            topk_idx[row * 3 + r] = found[r];
            topk_p[row * 3 + r] = expf(fval[r] - rowmax) / rowsum;
        }
    }
}

// ---------------- K4: att[b,ms,o] = sum_j p_j * (inputs[b,s_j,:]@WivT[o,:] + bvf[o])
__global__ __launch_bounds__(256) void k_att(const float* __restrict__ inputs,
                                             const float* __restrict__ WivT,
                                             const float* __restrict__ bvf,
                                             const float* __restrict__ topk_p,
                                             const int* __restrict__ topk_idx,
                                             float* __restrict__ att) {
    int bms = blockIdx.x;           // b*8 + ms
    int b = bms >> 3, ms = bms & 7;
    int t = threadIdx.x;
    for (int oo = 0; oo < 2; ++oo) {
        int o = oo * 256 + t;
        int h = o >> 6;
        int hm = h * 8 + ms;
        const float* wr = WivT + o * 256;
        float acc = 0.f;
#pragma unroll
        for (int j = 0; j < 3; ++j) {
            int sj = topk_idx[(b * 64 + hm) * 3 + j];
            float pj = topk_p[(b * 64 + hm) * 3 + j];
            const float* inr = inputs + ((size_t)b * SS + sj) * IN_;
            float dot = 0.f;
            for (int i = 0; i < 256; ++i) dot += inr[i] * wr[i];
            acc += pj * (dot + bvf[o]);
        }
        att[bms * 512 + o] = acc;
    }
}

// ---------------- K5 (MFMA): giacc[b,d] += sum_s relu(rw[d]*(inputs[b,s,:]@Wi[:,d] + bi[d]))
__global__ __launch_bounds__(256) void k_gimean_mfma(const float* __restrict__ inputs,
                                                     const unsigned short* __restrict__ WiTb,
                                                     const float* __restrict__ bi,
                                                     const float* __restrict__ rw,
                                                     float* __restrict__ giacc) {
    __shared__ unsigned short Al[64 * 256];
    __shared__ unsigned short Bl[64 * 256];
    __shared__ float gl[512];
    int t = threadIdx.x;
    int stile = blockIdx.x;   // 0..31
    int b = blockIdx.y;
    gl[t] = 0.f; gl[t + 256] = 0.f;

    const float* src = inputs + ((size_t)b * SS + stile * 64) * IN_;
    stage_tile_f32cvt(Al, src, t);
    __syncthreads();

    int l = t & 63, w = t >> 6;
    int kg = l >> 4, r16 = l & 15;
    short8 a[8];
#pragma unroll
    for (int kk = 0; kk < 8; ++kk) a[kk] = frag_ld(Al, w * 16 + r16, kk * 4 + kg);

    for (int dt = 0; dt < 8; ++dt) {
        __syncthreads();
        stage_tile_bf16(Bl, WiTb + (size_t)dt * 64 * 256, t);
        __syncthreads();
#pragma unroll
        for (int nt = 0; nt < 4; ++nt) {
            f32x4 acc = {0.f, 0.f, 0.f, 0.f};
#pragma unroll
            for (int kk = 0; kk < 8; ++kk) {
                short8 bf = frag_ld(Bl, nt * 16 + r16, kk * 4 + kg);
                acc = __builtin_amdgcn_mfma_f32_16x16x32_bf16(a[kk], bf, acc, 0, 0, 0);
            }
            int d = dt * 64 + nt * 16 + r16;
            float bid = bi[d], rwd = rw[d];
            float v = 0.f;
#pragma unroll
            for (int j = 0; j < 4; ++j) v += fmaxf(rwd * (acc[j] + bid), 0.f);
            v += __shfl_xor(v, 16);
            v += __shfl_xor(v, 32);
            if (kg == 0) atomicAdd(&gl[d], v);
        }
    }
    __syncthreads();
    atomicAdd(&giacc[b * 512 + t], gl[t]);
    atomicAdd(&giacc[b * 512 + 256 + t], gl[t + 256]);
}

// ---------------- K6a: gate_in[b,o] = (gi_acc[b,:]/S)@Wr + br
__global__ __launch_bounds__(256) void k_gatein(const float* __restrict__ gi_acc,
                                                const float* __restrict__ Wr,
                                                const float* __restrict__ br,
                                                float* __restrict__ gate_in) {
    int b = blockIdx.x;
    int t = threadIdx.x;
    __shared__ float gm[512];
    gm[t]       = gi_acc[b * 512 + t] * (1.0f / 2048.0f);
    gm[t + 256] = gi_acc[b * 512 + t + 256] * (1.0f / 2048.0f);
    __syncthreads();
    for (int oo = 0; oo < 4; ++oo) {
        int o = oo * 256 + t;
        float acc = br[o];
        for (int d = 0; d < 512; ++d) acc += gm[d] * Wr[d * 1024 + o];
        gate_in[b * 1024 + o] = acc;
    }
}

// ---------------- K6b: LN1 -> mlp x2 -> LN2 -> gates -> output
__global__ __launch_bounds__(256) void k_final(const float* __restrict__ memory,
                                               const float* __restrict__ att,
                                               const float* __restrict__ Wmlp,
                                               const float* __restrict__ bmlp,
                                               const float* __restrict__ g1,
                                               const float* __restrict__ b1,
                                               const float* __restrict__ g2,
                                               const float* __restrict__ b2,
                                               const float* __restrict__ Wg,
                                               const float* __restrict__ gate_in,
                                               const float* __restrict__ fb,
                                               const float* __restrict__ ib,
                                               float* __restrict__ out) {
    int bms = blockIdx.x;
    int b = bms >> 3, ms = bms & 7;
    int t = threadIdx.x;
    __shared__ float mem1[512];
    __shared__ float tmem[512];
    __shared__ float buf[512];
    __shared__ float red[256];

    float m0 = memory[bms * 512 + t], m1 = memory[bms * 512 + t + 256];
    float a0 = att[bms * 512 + t],    a1 = att[bms * 512 + t + 256];
    tmem[t] = tanhf(m0); tmem[t + 256] = tanhf(m1);
    float x0 = m0 + a0, x1 = m1 + a1;

    float mu = block_sum256(x0 + x1, red) * (1.f / 512.f);
    float d0 = x0 - mu, d1 = x1 - mu;
    float var = block_sum256(d0 * d0 + d1 * d1, red) * (1.f / 512.f);
    float rstd = rsqrtf(var + 1e-5f);
    mem1[t]       = d0 * rstd * g1[t] + b1[t];
    mem1[t + 256] = d1 * rstd * g1[t + 256] + b1[t + 256];
    __syncthreads();

    // mlp layer 1
    float r0 = bmlp[t], r1 = bmlp[t + 256];
    for (int d = 0; d < 512; ++d) {
        float md = mem1[d];
        r0 += md * Wmlp[d * 512 + t];
        r1 += md * Wmlp[d * 512 + t + 256];
    }
    r0 = fmaxf(r0, 0.f); r1 = fmaxf(r1, 0.f);
    buf[t] = r0; buf[t + 256] = r1;
    __syncthreads();

    // mlp layer 2 (shared weights)
    float q0 = bmlp[t], q1 = bmlp[t + 256];
    for (int d = 0; d < 512; ++d) {
        float md = buf[d];
        q0 += md * Wmlp[d * 512 + t];
        q1 += md * Wmlp[d * 512 + t + 256];
    }
    q0 = fmaxf(q0, 0.f); q1 = fmaxf(q1, 0.f);

    float y0 = mem1[t] + q0, y1 = mem1[t + 256] + q1;
    float mu2 = block_sum256(y0 + y1, red) * (1.f / 512.f);
    float e0 = y0 - mu2, e1 = y1 - mu2;
    float var2 = block_sum256(e0 * e0 + e1 * e1, red) * (1.f / 512.f);
    float rstd2 = rsqrtf(var2 + 1e-5f);
    float np0 = e0 * rstd2 * g2[t] + b2[t];
    float np1 = e1 * rstd2 * g2[t + 256] + b2[t + 256];

    // gates
    float ib_ = ib[0], fb_ = fb[0];
    const float* Wgm = Wg + (size_t)ms * 512 * 1024;
    float ig0 = gate_in[b * 1024 + t],       ig1 = gate_in[b * 1024 + t + 256];
    float fg0 = gate_in[b * 1024 + 512 + t], fg1 = gate_in[b * 1024 + 512 + t + 256];
    for (int j = 0; j < 512; ++j) {
        float tm = tmem[j];
        const float* wr = Wgm + (size_t)j * 1024;
        ig0 += tm * wr[t];       ig1 += tm * wr[t + 256];
        fg0 += tm * wr[512 + t]; fg1 += tm * wr[512 + t + 256];
    }
    float s_ig0 = 1.f / (1.f + expf(-(ig0 + ib_)));
    float s_ig1 = 1.f / (1.f + expf(-(ig1 + ib_)));
    float s_fg0 = 1.f / (1.f + expf(-(fg0 + fb_)));
    float s_fg1 = 1.f / (1.f + expf(-(fg1 + fb_)));
    out[bms * 512 + t]       = s_ig0 * tanhf(np0) + s_fg0 * m0;
    out[bms * 512 + t + 256] = s_ig1 * tanhf(np1) + s_fg1 * m1;
}

extern "C" void kernel_launch(void* const* d_in, const int* in_sizes, int n_in,
                              void* d_out, int out_size, void* d_ws, size_t ws_size,
                              hipStream_t stream) {
    const float* inputs = (const float*)d_in[0];
    const float* memory = (const float*)d_in[1];
    const float* Wq  = (const float*)d_in[2];
    const float* bq  = (const float*)d_in[3];
    const float* Wk  = (const float*)d_in[4];
    const float* bk  = (const float*)d_in[5];
    const float* Wv  = (const float*)d_in[6];
    const float* bv  = (const float*)d_in[7];
    const float* Wmlp= (const float*)d_in[8];
    const float* bmlp= (const float*)d_in[9];
    const float* g1  = (const float*)d_in[10];
    const float* b1  = (const float*)d_in[11];
    const float* g2  = (const float*)d_in[12];
    const float* b2  = (const float*)d_in[13];
    const float* Wi  = (const float*)d_in[14];
    const float* bi  = (const float*)d_in[15];
    const float* rw  = (const float*)d_in[16];
    const float* Wr  = (const float*)d_in[17];
    const float* br  = (const float*)d_in[18];
    const float* Wg  = (const float*)d_in[19];
    const float* fb  = (const float*)d_in[20];
    const float* ib  = (const float*)d_in[21];
    float* out = (float*)d_out;

    float* ws = (float*)d_ws;
    float* WikT   = ws + 0;                 // 512*256
    float* WivT   = ws + 131072;            // 512*256
    float* bkf    = ws + 262144;            // 512
    float* bvf    = ws + 262656;            // 512
    float* qbuf   = ws + 263168;            // 64*8*512
    unsigned short* Pb = (unsigned short*)(ws + 525312);   // 64*64*256 bf16 = 2,097,152 floats
    float* cbuf   = ws + 2622464;           // 64*64
    float* scores = ws + 2626560;           // 64*64*2048
    float* topkp  = ws + 11015168;          // 64*64*3
    int*   topki  = (int*)(ws + 11027456);  // 64*64*3
    float* att    = ws + 11039744;          // 64*8*512
    float* giacc  = ws + 11301888;          // 64*512
    float* gatein = ws + 11334656;          // 64*1024
    unsigned short* WiTb = (unsigned short*)(ws + 11400192); // 512*256 bf16

    hipMemsetAsync(giacc, 0, (size_t)BB * 512 * sizeof(float), stream);

    k_fuse_w<<<1024, 256, 0, stream>>>(Wi, Wk, Wv, bi, bk, bv, WikT, WivT, bkf, bvf);
    k_q<<<512, 256, 0, stream>>>(memory, Wq, bq, qbuf);
    k_p<<<4096, 256, 0, stream>>>(qbuf, WikT, bkf, Pb, cbuf);
    k_wiT<<<512, 256, 0, stream>>>(Wi, WiTb);
    k_scores_mfma<<<dim3(32, 64), 256, 0, stream>>>(inputs, Pb, cbuf, scores);
    k_topk<<<4096, 256, 0, stream>>>(scores, topkp, topki);
    k_att<<<512, 256, 0, stream>>>(inputs, WivT, bvf, topkp, topki, att);
    k_gimean_mfma<<<dim3(32, 64), 256, 0, stream>>>(inputs, WiTb, bi, rw, giacc);
    k_gatein<<<64, 256, 0, stream>>>(giacc, Wr, br, gatein);
    k_final<<<512, 256, 0, stream>>>(memory, att, Wmlp, bmlp, g1, b1, g2, b2, Wg,
                                     gatein, fb, ib, out);
}